// Round 5
// baseline (31.845 us; speedup 1.0000x reference)
//
#include <hip/hip_runtime.h>
#include <hip/hip_fp16.h>

// Problem geometry (fixed by the reference)
#define NROWS   32768      // out_features N
#define KTOT    8192       // in_features K
#define KP      1024       // packed bytes per row (each stored as one int32 on device)
#define GROUPS  64         // scale groups per row (K/128)

// Split-K byte-LUT design
#define SLICE_W 256        // weights per K-slice
#define SLICE_B 32         // packed bytes (int32 elements) per slice per row
#define NSLICES (KTOT / SLICE_W)        // 32
#define BLK     512        // threads per block (8 waves)
#define ROWS_PER_BLK 1024
#define RCHUNKS (NROWS / ROWS_PER_BLK)  // 32  -> grid 1024 = 4 blocks/CU exact
#define LUTPAD  264        // pad: build-write bank = (pos*8+byte)&31 -> 2-way (free)

// ---------------------------------------------------------------------------
// Pass 1: per-(row, group) UNSCALED partials -> pTh[g*NROWS + r] (__half).
// One block = one K-slice x 1024 rows. 33 KiB byte-LUT in LDS.
// Gray-code build: 1 add per LUT entry. Inner loop: 1 ds_read + 1 add / byte.
// ---------------------------------------------------------------------------
__global__ __launch_bounds__(BLK, 8)
void bitlin_partials(const float* __restrict__ x,
                     const int* __restrict__ packed,
                     __half* __restrict__ pTh)
{
    __shared__ float lut[SLICE_B][LUTPAD];

    const int s     = blockIdx.x & (NSLICES - 1);  // K-slice id
    const int chunk = blockIdx.x >> 5;             // row-chunk id
    const int tid   = threadIdx.x;

    // ---- Gray-code LUT build: thread owns (pos, low-nibble L), walks the
    // high nibble in reflected-Gray order (1 add per entry).
    {
        const int pos = tid >> 4;          // byte position in slice, 0..31
        const int L   = tid & 15;          // low-nibble value this thread owns
        float xs[8];
#pragma unroll
        for (int i = 0; i < 8; ++i) xs[i] = x[s * SLICE_W + pos * 8 + i];
        // base entry: byte = (high=0)<<4 | L
        float e = ((L & 1) ? xs[0] : -xs[0])
                + ((L & 2) ? xs[1] : -xs[1])
                + ((L & 4) ? xs[2] : -xs[2])
                + ((L & 8) ? xs[3] : -xs[3])
                - xs[4] - xs[5] - xs[6] - xs[7];
        const float t0 = 2.f * xs[4], t1 = 2.f * xs[5],
                    t2 = 2.f * xs[6], t3 = 2.f * xs[7];
        float* row = &lut[pos][L];         // entries at row[G*16], byte = G<<4|L
        row[ 0*16] = e;                    // Gray walk of high nibble G:
        e += t0; row[ 1*16] = e;           // 0,1,3,2,6,7,5,4,12,13,15,14,10,11,9,8
        e += t1; row[ 3*16] = e;
        e -= t0; row[ 2*16] = e;
        e += t2; row[ 6*16] = e;
        e += t0; row[ 7*16] = e;
        e -= t1; row[ 5*16] = e;
        e -= t0; row[ 4*16] = e;
        e += t3; row[12*16] = e;
        e += t0; row[13*16] = e;
        e += t1; row[15*16] = e;
        e -= t0; row[14*16] = e;
        e -= t2; row[10*16] = e;
        e += t0; row[11*16] = e;
        e -= t1; row[ 9*16] = e;
        e -= t0; row[ 8*16] = e;
    }
    __syncthreads();

    const int lane = tid & 63;
    const int wave = tid >> 6;       // 0..7
    const int sub  = lane & 7;       // which int4 (4 packed bytes) in the slice-row
    const int rsub = lane >> 3;      // row-within-8 for this wave-iteration
    const int rowBase = chunk * ROWS_PER_BLK + wave * (ROWS_PER_BLK / 8);

    const int4* __restrict__ p4 = (const int4*)packed;  // 4 packed bytes per int4

#pragma unroll 4
    for (int t = 0; t < 16; ++t) {
        const int r = rowBase + t * 8 + rsub;
        // coalesced: 8 lanes cover 128B of one row's slice, 8 rows per wave-load
        const int4 v = p4[r * (KP / 4) + s * (SLICE_B / 4) + sub];
        const int pos0 = sub * 4;
        float acc = lut[pos0 + 0][v.x & 255]
                  + lut[pos0 + 1][v.y & 255]
                  + lut[pos0 + 2][v.z & 255]
                  + lut[pos0 + 3][v.w & 255];
        // butterfly over the 4 lanes covering one group (128 weights)
        acc += __shfl_xor(acc, 1);
        acc += __shfl_xor(acc, 2);
        // lanes sub==0 (group 2s) and sub==4 (group 2s+1) store __half directly
        if ((sub & 3) == 0)
            pTh[(s * 2 + (sub >> 2)) * NROWS + r] = __float2half_rn(acc);
    }
}

// ---------------------------------------------------------------------------
// Pass 2: out[r] = sum_g pTh[g*NROWS + r] * scales[r*GROUPS + g]
// Block = 512 threads (8 waves) x 64 rows; wave w handles groups 8w..8w+7;
// cross-wave LDS reduce. All global reads coalesced; scales staged in LDS.
// ---------------------------------------------------------------------------
__global__ __launch_bounds__(512)
void bitlin_scale(const __half* __restrict__ pTh,
                  const float* __restrict__ scales,
                  float* __restrict__ out)
{
    __shared__ float s_s[64][65];    // padded: conflict-free column reads
    __shared__ float s_part[64][9];  // per-(row, wave) partials, padded

    const int tid     = threadIdx.x;
    const int lane    = tid & 63;
    const int wave    = tid >> 6;
    const int rowBase = blockIdx.x * 64;

    // stage 64 rows x 64 scales = 16 KiB, fully coalesced float4 loads
    const float4* s4 = (const float4*)(scales + (size_t)rowBase * GROUPS);
#pragma unroll
    for (int i = 0; i < 2; ++i) {
        const int idx = i * 512 + tid;        // 1024 float4 in the tile
        const float4 v = s4[idx];
        const int r = idx >> 4;               // 16 float4 per row
        const int c = (idx & 15) * 4;
        s_s[r][c + 0] = v.x;
        s_s[r][c + 1] = v.y;
        s_s[r][c + 2] = v.z;
        s_s[r][c + 3] = v.w;
    }
    __syncthreads();

    const int r = rowBase + lane;
    float acc = 0.f;
#pragma unroll
    for (int i = 0; i < 8; ++i) {
        const int g = wave * 8 + i;
        acc += __half2float(pTh[(size_t)g * NROWS + r]) * s_s[lane][g];
    }
    s_part[lane][wave] = acc;
    __syncthreads();

    if (wave == 0) {
        float a = 0.f;
#pragma unroll
        for (int w = 0; w < 8; ++w) a += s_part[lane][w];
        out[r] = a;
    }
}

// ---------------------------------------------------------------------------
// Fallback (proven Round-2 path) if ws can't hold the 4.2 MB partial matrix.
// ---------------------------------------------------------------------------
__global__ __launch_bounds__(BLK, 4)
void bitlin_main_atomic(const float* __restrict__ x,
                        const int* __restrict__ packed,
                        const float* __restrict__ scales,
                        float* __restrict__ ws)
{
    __shared__ float lut[SLICE_B][256];
    const int s     = blockIdx.x & (NSLICES - 1);
    const int chunk = blockIdx.x >> 5;
    const int tid   = threadIdx.x;
    {
        const int pos = tid >> 4;
        const int b0  = (tid & 15) << 4;
        float xs[8];
#pragma unroll
        for (int i = 0; i < 8; ++i) xs[i] = x[s * SLICE_W + pos * 8 + i];
#pragma unroll
        for (int b = 0; b < 16; ++b) {
            const int byte = b0 + b;
            float v = 0.f;
#pragma unroll
            for (int i = 0; i < 8; ++i)
                v += ((byte >> i) & 1) ? xs[i] : -xs[i];
            lut[pos][byte] = v;
        }
    }
    __syncthreads();

    const int lane = tid & 63;
    const int wave = tid >> 6;
    const int sub  = lane & 7;
    const int rsub = lane >> 3;
    const int rowBase = chunk * 512 + wave * 64;
    const int4* __restrict__ p4 = (const int4*)packed;

#pragma unroll
    for (int t = 0; t < 8; ++t) {
        const int r = rowBase + t * 8 + rsub;
        const int4 v = p4[r * (KP / 4) + s * (SLICE_B / 4) + sub];
        const float sc = scales[r * GROUPS + s * 2 + (sub >> 2)];
        const int pos0 = sub * 4;
        float acc = lut[pos0 + 0][v.x & 255]
                  + lut[pos0 + 1][v.y & 255]
                  + lut[pos0 + 2][v.z & 255]
                  + lut[pos0 + 3][v.w & 255];
        acc *= sc;
        acc += __shfl_xor(acc, 1);
        acc += __shfl_xor(acc, 2);
        acc += __shfl_xor(acc, 4);
        if (sub == 0) atomicAdd(&ws[r], acc);
    }
}

__global__ __launch_bounds__(512)
void bitlin_fin(const float* __restrict__ ws, float* __restrict__ out)
{
    const int i = blockIdx.x * blockDim.x + threadIdx.x;
    out[i] = ws[i];
}

extern "C" void kernel_launch(void* const* d_in, const int* in_sizes, int n_in,
                              void* d_out, int out_size, void* d_ws, size_t ws_size,
                              hipStream_t stream)
{
    const float* x      = (const float*)d_in[0];
    const int*   packed = (const int*)d_in[1];
    const float* scales = (const float*)d_in[2];

    const size_t pTh_bytes = (size_t)GROUPS * NROWS * sizeof(__half);  // 4.2 MB

    if (ws_size >= pTh_bytes) {
        __half* pTh = (__half*)d_ws;
        bitlin_partials<<<dim3(NSLICES * RCHUNKS), dim3(BLK), 0, stream>>>(x, packed, pTh);
        bitlin_scale<<<dim3(NROWS / 64), dim3(512), 0, stream>>>(pTh, scales, (float*)d_out);
    } else {
        // fallback: proven Round-2 fused path
        float* ws = (float*)d_ws;
        hipMemsetAsync(ws, 0, NROWS * sizeof(float), stream);
        bitlin_main_atomic<<<dim3(NSLICES * (NROWS / 512)), dim3(BLK), 0, stream>>>(x, packed, scales, ws);
        bitlin_fin<<<dim3(NROWS / 512), dim3(512), 0, stream>>>(ws, (float*)d_out);
    }
}